// Round 8
// baseline (245.333 us; speedup 1.0000x reference)
//
#include <hip/hip_runtime.h>

typedef unsigned short u16;
typedef __bf16 bf16x8 __attribute__((ext_vector_type(8)));
typedef float f32x4 __attribute__((ext_vector_type(4)));

// fp32 -> bf16 bits, round-to-nearest-even (finite inputs only)
__device__ __forceinline__ u16 f2bf(float f) {
  union { float f; unsigned u; } v; v.f = f;
  return (u16)((v.u + 0x7fffu + ((v.u >> 16) & 1u)) >> 16);
}

// pack two fp32 -> bf16x2 dword (round-half-up), low = lo, high = hi
__device__ __forceinline__ unsigned pkbf(float lo, float hi) {
  union { float f; unsigned u; } a, b; a.f = lo; b.f = hi;
  return __builtin_amdgcn_perm(b.u + 0x8000u, a.u + 0x8000u, 0x07060302u);
}

__device__ __forceinline__ float fexp2(float x) {
#if __has_builtin(__builtin_amdgcn_exp2f)
  return __builtin_amdgcn_exp2f(x);
#else
  return exp2f(x);
#endif
}

// async global->LDS, 16B per lane; LDS dst = base + lane*16 (wave-uniform base)
__device__ __forceinline__ void gld16(const u16* g, u16* l) {
  __builtin_amdgcn_global_load_lds(
      (const __attribute__((address_space(1))) void*)g,
      (__attribute__((address_space(3))) void*)l, 16, 0, 0);
}

// ---------------------------------------------------------------------------
// fp32 -> bf16 bulk convert for all three inputs in ONE dispatch.
// blocks [0,2048): x (4096x1024); [2048,3584): w_attn (3072x1024);
// [3584,4096): w_proj (1024x1024). 8 elems/thread, exact multiples.
// ---------------------------------------------------------------------------
__global__ __launch_bounds__(256) void cvt3(
    const float* __restrict__ x, const float* __restrict__ wa,
    const float* __restrict__ wp, u16* __restrict__ xb,
    u16* __restrict__ wab, u16* __restrict__ wpb)
{
  int b = blockIdx.x;
  const float* in; u16* out; int i;
  if (b < 2048)      { in = x;  out = xb;  i = b * 256 + threadIdx.x; }
  else if (b < 3584) { in = wa; out = wab; i = (b - 2048) * 256 + threadIdx.x; }
  else               { in = wp; out = wpb; i = (b - 3584) * 256 + threadIdx.x; }
  const float* p = in + (size_t)i * 8;
  float4 a = *(const float4*)p, c = *(const float4*)(p + 4);
  uint4 o;
  o.x = pkbf(a.x, a.y); o.y = pkbf(a.z, a.w);
  o.z = pkbf(c.x, c.y); o.w = pkbf(c.z, c.w);
  *(uint4*)&out[(size_t)i * 8] = o;
}

// ---------------------------------------------------------------------------
// m97-style GEMM: C[M,N] = A[M,K]*B[N,K]^T, bf16 in, fp32 acc.
// global_load_lds width-16 staging, unpadded As/Bs[128][32], 2-barrier K-loop.
// VSPLIT: n0>=2048 blocks write V TRANSPOSED to C2 (vT[1024][4096]) in
// pi-permuted key order: pos(k) = (k>>5)*32 + 2*(k&15) + ((k>>4)&1).
// launch_bounds min 3 waves/EU -> VGPR<=170 -> 3 blocks/CU.
// ---------------------------------------------------------------------------
template<bool COUT_F32, bool VSPLIT>
__global__ __launch_bounds__(256, 3) void gemm_lds(
    const u16* __restrict__ A, const u16* __restrict__ B, void* __restrict__ C,
    u16* __restrict__ C2, int M, int N, int K, int ldc)
{
  __shared__ u16 S[9216];            // As[128][32]@0, Bs[128][32]@4096; epilogue overlay
  u16* As = S;
  u16* Bs = S + 4096;
  const int tid  = threadIdx.x;
  const int wave = tid >> 6, lane = tid & 63;
  const int quad = lane >> 4, ln = lane & 15;
  const int m0 = blockIdx.y * 128, n0 = blockIdx.x * 128;
  const int wm = (wave >> 1) * 64, wn = (wave & 1) * 64;

  const int srow = wave * 32 + (lane >> 2);
  const int scol = (lane & 3) * 8;

  f32x4 acc[4][4] = {};

  for (int k0 = 0; k0 < K; k0 += 32) {
    __syncthreads();
    const u16* ga = A + (size_t)(m0 + srow) * K + k0 + scol;
    const u16* gb = B + (size_t)(n0 + srow) * K + k0 + scol;
    gld16(ga,                  As + wave * 1024);
    gld16(ga + (size_t)16 * K, As + wave * 1024 + 512);
    gld16(gb,                  Bs + wave * 1024);
    gld16(gb + (size_t)16 * K, Bs + wave * 1024 + 512);
    __syncthreads();

    bf16x8 af[4], bfr[4];
#pragma unroll
    for (int i = 0; i < 4; ++i) af[i]  = *(const bf16x8*)&As[(wm + i * 16 + ln) * 32 + quad * 8];
#pragma unroll
    for (int j = 0; j < 4; ++j) bfr[j] = *(const bf16x8*)&Bs[(wn + j * 16 + ln) * 32 + quad * 8];
#pragma unroll
    for (int i = 0; i < 4; ++i)
#pragma unroll
      for (int j = 0; j < 4; ++j)
        acc[i][j] = __builtin_amdgcn_mfma_f32_16x16x32_bf16(af[i], bfr[j], acc[i][j], 0, 0, 0);
  }

  if constexpr (VSPLIT) {
    if (n0 >= 2048) {
      u16 (*Cs)[72] = (u16(*)[72])S;
      __syncthreads();
#pragma unroll
      for (int c = 0; c < 2; ++c) {
        if ((wave >> 1) == c) {
#pragma unroll
          for (int i = 0; i < 4; ++i)
#pragma unroll
            for (int j = 0; j < 4; ++j)
#pragma unroll
              for (int r = 0; r < 4; ++r) {
                int pos = (i >> 1) * 32 + (quad * 4 + r) * 2 + (i & 1);  // pi(m-in-chunk)
                Cs[wn + j * 16 + ln][pos] = f2bf(acc[i][j][r]);
              }
        }
        __syncthreads();
        {
          int nl = tid >> 1, mseg = (tid & 1) * 32;
#pragma unroll
          for (int s2 = 0; s2 < 4; ++s2) {
            uint4 v4 = *(const uint4*)&Cs[nl][mseg + s2 * 8];
            *(uint4*)&C2[(size_t)(n0 - 2048 + nl) * 4096 + m0 + c * 64 + mseg + s2 * 8] = v4;
          }
        }
        __syncthreads();
      }
      return;
    }
  }

#pragma unroll
  for (int i = 0; i < 4; ++i)
#pragma unroll
    for (int j = 0; j < 4; ++j)
#pragma unroll
      for (int r = 0; r < 4; ++r) {
        int m = m0 + wm + i * 16 + quad * 4 + r;   // C/D: row = quad*4+reg
        int n = n0 + wn + j * 16 + ln;             //      col = lane&15
        if constexpr (COUT_F32)
          ((float*)C)[(size_t)m * ldc + n] = acc[i][j][r];
        else
          ((u16*)C)[(size_t)m * ldc + n] = f2bf(acc[i][j][r]);
      }
}

// ---------------------------------------------------------------------------
// Fallback GEMM (fp32 staging) — used only if ws_size < 40 MiB.
// ---------------------------------------------------------------------------
template<bool F32>
__device__ __forceinline__ void stage8(u16* dst, const void* base, size_t off) {
  if constexpr (F32) {
    const float* p = (const float*)base + off;
    float4 a = *(const float4*)p;
    float4 b = *(const float4*)(p + 4);
    uint4 q;
    q.x = pkbf(a.x, a.y); q.y = pkbf(a.z, a.w);
    q.z = pkbf(b.x, b.y); q.w = pkbf(b.z, b.w);
    *(uint4*)dst = q;
  } else {
    *(uint4*)dst = *(const uint4*)((const u16*)base + off);
  }
}

template<bool AF32, bool BF32, bool COUT_F32, bool VSPLIT>
__global__ __launch_bounds__(256) void gemm_bt(
    const void* __restrict__ A, const void* __restrict__ B, void* __restrict__ C,
    u16* __restrict__ C2, int M, int N, int K, int ldc)
{
  __shared__ u16 As[128][40];
  __shared__ u16 Bs[128][40];
  const int tid  = threadIdx.x;
  const int wave = tid >> 6, lane = tid & 63;
  const int quad = lane >> 4, ln = lane & 15;
  const int m0 = blockIdx.y * 128, n0 = blockIdx.x * 128;
  const int wm = (wave >> 1) * 64, wn = (wave & 1) * 64;

  f32x4 acc[4][4] = {};

  for (int k0 = 0; k0 < K; k0 += 32) {
    __syncthreads();
#pragma unroll
    for (int i = 0; i < 2; ++i) {
      int idx = tid + i * 256;
      int row = idx >> 2, seg = (idx & 3) * 8;
      stage8<AF32>(&As[row][seg], A, (size_t)(m0 + row) * K + k0 + seg);
      stage8<BF32>(&Bs[row][seg], B, (size_t)(n0 + row) * K + k0 + seg);
    }
    __syncthreads();
    bf16x8 af[4], bfr[4];
#pragma unroll
    for (int i = 0; i < 4; ++i) af[i]  = *(const bf16x8*)&As[wm + i * 16 + ln][quad * 8];
#pragma unroll
    for (int j = 0; j < 4; ++j) bfr[j] = *(const bf16x8*)&Bs[wn + j * 16 + ln][quad * 8];
#pragma unroll
    for (int i = 0; i < 4; ++i)
#pragma unroll
      for (int j = 0; j < 4; ++j)
        acc[i][j] = __builtin_amdgcn_mfma_f32_16x16x32_bf16(af[i], bfr[j], acc[i][j], 0, 0, 0);
  }

  if constexpr (VSPLIT) {
    if (n0 >= 2048) {
      __shared__ u16 Cs[128][72];
#pragma unroll
      for (int c = 0; c < 2; ++c) {
        if ((wave >> 1) == c) {
#pragma unroll
          for (int i = 0; i < 4; ++i)
#pragma unroll
            for (int j = 0; j < 4; ++j)
#pragma unroll
              for (int r = 0; r < 4; ++r) {
                int pos = (i >> 1) * 32 + (quad * 4 + r) * 2 + (i & 1);
                Cs[wn + j * 16 + ln][pos] = f2bf(acc[i][j][r]);
              }
        }
        __syncthreads();
        {
          int nl = tid >> 1, mseg = (tid & 1) * 32;
#pragma unroll
          for (int s2 = 0; s2 < 4; ++s2) {
            uint4 v4 = *(const uint4*)&Cs[nl][mseg + s2 * 8];
            *(uint4*)&C2[(size_t)(n0 - 2048 + nl) * 4096 + m0 + c * 64 + mseg + s2 * 8] = v4;
          }
        }
        __syncthreads();
      }
      return;
    }
  }

#pragma unroll
  for (int i = 0; i < 4; ++i)
#pragma unroll
    for (int j = 0; j < 4; ++j)
#pragma unroll
      for (int r = 0; r < 4; ++r) {
        int m = m0 + wm + i * 16 + quad * 4 + r;
        int n = n0 + wn + j * 16 + ln;
        if constexpr (COUT_F32)
          ((float*)C)[(size_t)m * ldc + n] = acc[i][j][r];
        else
          ((u16*)C)[(size_t)m * ldc + n] = f2bf(acc[i][j][r]);
      }
}

// ---------------------------------------------------------------------------
// Causal flash attention (MFMA), fixed-base softmax, async K/V staging via
// global_load_lds into unpadded double-buffered tiles (one barrier per tile).
// Grid 64x16, qt = 63-bx (heavy first), 3 blocks/CU (42 KB LDS).
// ---------------------------------------------------------------------------
__global__ __launch_bounds__(256, 3) void attn_fwd(
    const u16* __restrict__ qk, const u16* __restrict__ vT, u16* __restrict__ y)
{
  __shared__ u16 Ks[2][2][64][32];   // [buf][d-half][key][d%32]
  __shared__ u16 Vt[2][2][64][32];   // [buf][pi-key-half][d][pos%32]
  __shared__ u16 Ps[4][2][16][40];   // per-wave P relay (pi-key order)

  const int tid  = threadIdx.x;
  const int wave = tid >> 6, lane = tid & 63;
  const int quad = lane >> 4, ln = lane & 15;
  const int h  = blockIdx.y;
  const int qt = 63 - (int)blockIdx.x;
  const int q0w = qt * 64 + wave * 16;
  const float C1 = 0.18033688f;      // 0.125 * log2(e)

  // async stage of K/V tile kt into buffer b: 16 x 1KB issues, 4 per wave
  auto stage = [&](int b, int kt) {
#pragma unroll
    for (int i = 0; i < 4; ++i) {
      int e = wave + 4 * i;          // wave-uniform issue id
      int half = e & 1, rg = (e >> 1) & 3;
      if (e < 8) {
        const u16* g = qk + (size_t)(kt * 64 + rg * 16 + (lane >> 2)) * 2048
                       + 1024 + h * 64 + half * 32 + (lane & 3) * 8;
        gld16(g, &Ks[b][half][rg * 16][0]);
      } else {
        const u16* g = vT + (size_t)(h * 64 + rg * 16 + (lane >> 2)) * 4096
                       + kt * 64 + half * 32 + (lane & 3) * 8;
        gld16(g, &Vt[b][half][rg * 16][0]);
      }
    }
  };

  bf16x8 qa0, qa1;
  {
    const u16* qrow = qk + (size_t)(q0w + ln) * 2048 + h * 64;
    qa0 = *(const bf16x8*)(qrow + quad * 8);
    qa1 = *(const bf16x8*)(qrow + 32 + quad * 8);
  }

  f32x4 o[4] = {};
  float l_i[4] = {0.f, 0.f, 0.f, 0.f};

  stage(0, 0);
  int b = 0;
  for (int kt = 0; kt <= qt; ++kt, b ^= 1) {
    __syncthreads();                 // drains vmcnt(0): buf b ready, buf b^1 free
    if (kt < qt) stage(b ^ 1, kt + 1);

    // S = Q K^T (16 x 64): 4 col-tiles, contraction 64 = 2 chained MFMA
    f32x4 s[4];
#pragma unroll
    for (int c = 0; c < 4; ++c) {
      f32x4 z = {0.f, 0.f, 0.f, 0.f};
      z = __builtin_amdgcn_mfma_f32_16x16x32_bf16(qa0, *(const bf16x8*)&Ks[b][0][c * 16 + ln][quad * 8], z, 0, 0, 0);
      z = __builtin_amdgcn_mfma_f32_16x16x32_bf16(qa1, *(const bf16x8*)&Ks[b][1][c * 16 + ln][quad * 8], z, 0, 0, 0);
      s[c] = z;
    }

    // V fragments early (lgkm drained by the relay waitcnt below anyway)
    bf16x8 vb0[4], vb1[4];
#pragma unroll
    for (int dt = 0; dt < 4; ++dt) {
      vb0[dt] = *(const bf16x8*)&Vt[b][0][dt * 16 + ln][quad * 8];
      vb1[dt] = *(const bf16x8*)&Vt[b][1][dt * 16 + ln][quad * 8];
    }

    // fixed-base softmax: p = 2^(qk*C1 - 46); mask only on diagonal tile
    float p[4][4];   // [c][r]
    if (kt < qt) {
#pragma unroll
      for (int c = 0; c < 4; ++c)
#pragma unroll
        for (int r = 0; r < 4; ++r)
          p[c][r] = fexp2(fmaf(s[c][r], C1, -46.0f));
    } else {
      const int rowb = q0w + quad * 4;
#pragma unroll
      for (int c = 0; c < 4; ++c) {
        int col = kt * 64 + c * 16 + ln;
#pragma unroll
        for (int r = 0; r < 4; ++r) {
          float arg = (col > rowb + r) ? -200.0f : fmaf(s[c][r], C1, -46.0f);
          p[c][r] = fexp2(arg);
        }
      }
    }
#pragma unroll
    for (int r = 0; r < 4; ++r)
      l_i[r] += (p[0][r] + p[1][r]) + (p[2][r] + p[3][r]);

    // pack P (pi order) -> per-wave LDS relay -> A-layout fragments
#pragma unroll
    for (int r = 0; r < 4; ++r) {
#pragma unroll
      for (int H = 0; H < 2; ++H)
        *(unsigned*)&Ps[wave][H][quad * 4 + r][ln * 2] = pkbf(p[2 * H][r], p[2 * H + 1][r]);
    }
    __asm__ volatile("s_waitcnt lgkmcnt(0)" ::: "memory");  // wave-local relay
    bf16x8 pa0 = *(const bf16x8*)&Ps[wave][0][ln][quad * 8];
    bf16x8 pa1 = *(const bf16x8*)&Ps[wave][1][ln][quad * 8];
#pragma unroll
    for (int dt = 0; dt < 4; ++dt) {
      f32x4 z = o[dt];
      z = __builtin_amdgcn_mfma_f32_16x16x32_bf16(pa0, vb0[dt], z, 0, 0, 0);
      z = __builtin_amdgcn_mfma_f32_16x16x32_bf16(pa1, vb1[dt], z, 0, 0, 0);
      o[dt] = z;
    }
  }

  // deferred l reduction across the 16 lanes of each quad-row
#pragma unroll
  for (int r = 0; r < 4; ++r) {
#pragma unroll
    for (int off = 8; off > 0; off >>= 1) l_i[r] += __shfl_xor(l_i[r], off, 16);
  }
#pragma unroll
  for (int r = 0; r < 4; ++r) {
    float inv = 1.0f / l_i[r];
    int rowg = q0w + quad * 4 + r;
#pragma unroll
    for (int dt = 0; dt < 4; ++dt)
      y[(size_t)rowg * 1024 + h * 64 + dt * 16 + ln] = f2bf(o[dt][r] * inv);
  }
}

extern "C" void kernel_launch(void* const* d_in, const int* in_sizes, int n_in,
                              void* d_out, int out_size, void* d_ws, size_t ws_size,
                              hipStream_t stream) {
  const float* x      = (const float*)d_in[0];   // [4096,1024] fp32
  const float* w_attn = (const float*)d_in[1];   // [3072,1024] fp32
  const float* w_proj = (const float*)d_in[2];   // [1024,1024] fp32

  char* ws = (char*)d_ws;
  u16* qk = (u16*)ws;                        // 16 MiB [4096][2048]
  u16* vT = (u16*)(ws + (16u << 20));        //  8 MiB [1024][4096] pi-permuted

  if (ws_size >= (size_t)(40u << 20)) {
    u16* wpb = (u16*)(ws + (24u << 20));     //  2 MiB bf16 w_proj
    u16* xb  = (u16*)(ws + (26u << 20));     //  8 MiB bf16 x   (dead after GEMM1)
    u16* wab = (u16*)(ws + (34u << 20));     //  6 MiB bf16 w_attn (dead after GEMM1)
    u16* y   = (u16*)(ws + (26u << 20));     //  8 MiB, overlays xb (lifetime-disjoint)

    cvt3<<<4096, 256, 0, stream>>>(x, w_attn, w_proj, xb, wab, wpb);
    gemm_lds<false, true><<<dim3(24, 32), 256, 0, stream>>>(
        xb, wab, qk, vT, 4096, 3072, 1024, 2048);
    attn_fwd<<<dim3(64, 16), 256, 0, stream>>>(qk, vT, y);
    gemm_lds<true, false><<<dim3(8, 32), 256, 0, stream>>>(
        y, wpb, d_out, nullptr, 4096, 1024, 1024, 1024);
  } else {
    u16* y = (u16*)(ws + (24u << 20));
    gemm_bt<true, true, false, true><<<dim3(24, 32), 256, 0, stream>>>(
        x, w_attn, qk, vT, 4096, 3072, 1024, 2048);
    attn_fwd<<<dim3(64, 16), 256, 0, stream>>>(qk, vT, y);
    gemm_bt<false, true, true, false><<<dim3(8, 32), 256, 0, stream>>>(
        y, w_proj, d_out, nullptr, 4096, 1024, 1024, 1024);
  }
}

// Round 9
// 217.818 us; speedup vs baseline: 1.1263x; 1.1263x over previous
//
#include <hip/hip_runtime.h>

typedef unsigned short u16;
typedef __bf16 bf16x8 __attribute__((ext_vector_type(8)));
typedef float f32x4 __attribute__((ext_vector_type(4)));

// fp32 -> bf16 bits, round-to-nearest-even (finite inputs only)
__device__ __forceinline__ u16 f2bf(float f) {
  union { float f; unsigned u; } v; v.f = f;
  return (u16)((v.u + 0x7fffu + ((v.u >> 16) & 1u)) >> 16);
}

// pack two fp32 -> bf16x2 dword (round-half-up), low = lo, high = hi
__device__ __forceinline__ unsigned pkbf(float lo, float hi) {
  union { float f; unsigned u; } a, b; a.f = lo; b.f = hi;
  return __builtin_amdgcn_perm(b.u + 0x8000u, a.u + 0x8000u, 0x07060302u);
}

__device__ __forceinline__ float fexp2(float x) {
#if __has_builtin(__builtin_amdgcn_exp2f)
  return __builtin_amdgcn_exp2f(x);
#else
  return exp2f(x);
#endif
}

// async global->LDS, 16B per lane; LDS dst = base + lane*16 (wave-uniform base)
__device__ __forceinline__ void gld16(const u16* g, u16* l) {
  __builtin_amdgcn_global_load_lds(
      (const __attribute__((address_space(1))) void*)g,
      (__attribute__((address_space(3))) void*)l, 16, 0, 0);
}

// ---------------------------------------------------------------------------
// fp32 -> bf16 bulk convert for all three inputs in ONE dispatch.
// ---------------------------------------------------------------------------
__global__ __launch_bounds__(256) void cvt3(
    const float* __restrict__ x, const float* __restrict__ wa,
    const float* __restrict__ wp, u16* __restrict__ xb,
    u16* __restrict__ wab, u16* __restrict__ wpb)
{
  int b = blockIdx.x;
  const float* in; u16* out; int i;
  if (b < 2048)      { in = x;  out = xb;  i = b * 256 + threadIdx.x; }
  else if (b < 3584) { in = wa; out = wab; i = (b - 2048) * 256 + threadIdx.x; }
  else               { in = wp; out = wpb; i = (b - 3584) * 256 + threadIdx.x; }
  const float* p = in + (size_t)i * 8;
  float4 a = *(const float4*)p, c = *(const float4*)(p + 4);
  uint4 o;
  o.x = pkbf(a.x, a.y); o.y = pkbf(a.z, a.w);
  o.z = pkbf(c.x, c.y); o.w = pkbf(c.z, c.w);
  *(uint4*)&out[(size_t)i * 8] = o;
}

// ---------------------------------------------------------------------------
// m97-style GEMM: C[M,N] = A[M,K]*B[N,K]^T, bf16 in, fp32 acc.
// VSPLIT: n0>=2048 blocks write V TRANSPOSED to C2 (vT[1024][4096]) in
// pi-permuted key order: pos(k) = (k>>5)*32 + 2*(k&15) + ((k>>4)&1).
// ---------------------------------------------------------------------------
template<bool COUT_F32, bool VSPLIT>
__global__ __launch_bounds__(256, 3) void gemm_lds(
    const u16* __restrict__ A, const u16* __restrict__ B, void* __restrict__ C,
    u16* __restrict__ C2, int M, int N, int K, int ldc)
{
  __shared__ u16 S[9216];
  u16* As = S;
  u16* Bs = S + 4096;
  const int tid  = threadIdx.x;
  const int wave = tid >> 6, lane = tid & 63;
  const int quad = lane >> 4, ln = lane & 15;
  const int m0 = blockIdx.y * 128, n0 = blockIdx.x * 128;
  const int wm = (wave >> 1) * 64, wn = (wave & 1) * 64;

  const int srow = wave * 32 + (lane >> 2);
  const int scol = (lane & 3) * 8;

  f32x4 acc[4][4] = {};

  for (int k0 = 0; k0 < K; k0 += 32) {
    __syncthreads();
    const u16* ga = A + (size_t)(m0 + srow) * K + k0 + scol;
    const u16* gb = B + (size_t)(n0 + srow) * K + k0 + scol;
    gld16(ga,                  As + wave * 1024);
    gld16(ga + (size_t)16 * K, As + wave * 1024 + 512);
    gld16(gb,                  Bs + wave * 1024);
    gld16(gb + (size_t)16 * K, Bs + wave * 1024 + 512);
    __syncthreads();

    bf16x8 af[4], bfr[4];
#pragma unroll
    for (int i = 0; i < 4; ++i) af[i]  = *(const bf16x8*)&As[(wm + i * 16 + ln) * 32 + quad * 8];
#pragma unroll
    for (int j = 0; j < 4; ++j) bfr[j] = *(const bf16x8*)&Bs[(wn + j * 16 + ln) * 32 + quad * 8];
#pragma unroll
    for (int i = 0; i < 4; ++i)
#pragma unroll
      for (int j = 0; j < 4; ++j)
        acc[i][j] = __builtin_amdgcn_mfma_f32_16x16x32_bf16(af[i], bfr[j], acc[i][j], 0, 0, 0);
  }

  if constexpr (VSPLIT) {
    if (n0 >= 2048) {
      u16 (*Cs)[72] = (u16(*)[72])S;
      __syncthreads();
#pragma unroll
      for (int c = 0; c < 2; ++c) {
        if ((wave >> 1) == c) {
#pragma unroll
          for (int i = 0; i < 4; ++i)
#pragma unroll
            for (int j = 0; j < 4; ++j)
#pragma unroll
              for (int r = 0; r < 4; ++r) {
                int pos = (i >> 1) * 32 + (quad * 4 + r) * 2 + (i & 1);  // pi(m-in-chunk)
                Cs[wn + j * 16 + ln][pos] = f2bf(acc[i][j][r]);
              }
        }
        __syncthreads();
        {
          int nl = tid >> 1, mseg = (tid & 1) * 32;
#pragma unroll
          for (int s2 = 0; s2 < 4; ++s2) {
            uint4 v4 = *(const uint4*)&Cs[nl][mseg + s2 * 8];
            *(uint4*)&C2[(size_t)(n0 - 2048 + nl) * 4096 + m0 + c * 64 + mseg + s2 * 8] = v4;
          }
        }
        __syncthreads();
      }
      return;
    }
  }

#pragma unroll
  for (int i = 0; i < 4; ++i)
#pragma unroll
    for (int j = 0; j < 4; ++j)
#pragma unroll
      for (int r = 0; r < 4; ++r) {
        int m = m0 + wm + i * 16 + quad * 4 + r;   // C/D: row = quad*4+reg
        int n = n0 + wn + j * 16 + ln;             //      col = lane&15
        if constexpr (COUT_F32)
          ((float*)C)[(size_t)m * ldc + n] = acc[i][j][r];
        else
          ((u16*)C)[(size_t)m * ldc + n] = f2bf(acc[i][j][r]);
      }
}

// ---------------------------------------------------------------------------
// Fallback GEMM (fp32 staging) — used only if ws_size < 40 MiB.
// ---------------------------------------------------------------------------
template<bool F32>
__device__ __forceinline__ void stage8(u16* dst, const void* base, size_t off) {
  if constexpr (F32) {
    const float* p = (const float*)base + off;
    float4 a = *(const float4*)p;
    float4 b = *(const float4*)(p + 4);
    uint4 q;
    q.x = pkbf(a.x, a.y); q.y = pkbf(a.z, a.w);
    q.z = pkbf(b.x, b.y); q.w = pkbf(b.z, b.w);
    *(uint4*)dst = q;
  } else {
    *(uint4*)dst = *(const uint4*)((const u16*)base + off);
  }
}

template<bool AF32, bool BF32, bool COUT_F32, bool VSPLIT>
__global__ __launch_bounds__(256) void gemm_bt(
    const void* __restrict__ A, const void* __restrict__ B, void* __restrict__ C,
    u16* __restrict__ C2, int M, int N, int K, int ldc)
{
  __shared__ u16 As[128][40];
  __shared__ u16 Bs[128][40];
  const int tid  = threadIdx.x;
  const int wave = tid >> 6, lane = tid & 63;
  const int quad = lane >> 4, ln = lane & 15;
  const int m0 = blockIdx.y * 128, n0 = blockIdx.x * 128;
  const int wm = (wave >> 1) * 64, wn = (wave & 1) * 64;

  f32x4 acc[4][4] = {};

  for (int k0 = 0; k0 < K; k0 += 32) {
    __syncthreads();
#pragma unroll
    for (int i = 0; i < 2; ++i) {
      int idx = tid + i * 256;
      int row = idx >> 2, seg = (idx & 3) * 8;
      stage8<AF32>(&As[row][seg], A, (size_t)(m0 + row) * K + k0 + seg);
      stage8<BF32>(&Bs[row][seg], B, (size_t)(n0 + row) * K + k0 + seg);
    }
    __syncthreads();
    bf16x8 af[4], bfr[4];
#pragma unroll
    for (int i = 0; i < 4; ++i) af[i]  = *(const bf16x8*)&As[wm + i * 16 + ln][quad * 8];
#pragma unroll
    for (int j = 0; j < 4; ++j) bfr[j] = *(const bf16x8*)&Bs[wn + j * 16 + ln][quad * 8];
#pragma unroll
    for (int i = 0; i < 4; ++i)
#pragma unroll
      for (int j = 0; j < 4; ++j)
        acc[i][j] = __builtin_amdgcn_mfma_f32_16x16x32_bf16(af[i], bfr[j], acc[i][j], 0, 0, 0);
  }

  if constexpr (VSPLIT) {
    if (n0 >= 2048) {
      __shared__ u16 Cs[128][72];
#pragma unroll
      for (int c = 0; c < 2; ++c) {
        if ((wave >> 1) == c) {
#pragma unroll
          for (int i = 0; i < 4; ++i)
#pragma unroll
            for (int j = 0; j < 4; ++j)
#pragma unroll
              for (int r = 0; r < 4; ++r) {
                int pos = (i >> 1) * 32 + (quad * 4 + r) * 2 + (i & 1);
                Cs[wn + j * 16 + ln][pos] = f2bf(acc[i][j][r]);
              }
        }
        __syncthreads();
        {
          int nl = tid >> 1, mseg = (tid & 1) * 32;
#pragma unroll
          for (int s2 = 0; s2 < 4; ++s2) {
            uint4 v4 = *(const uint4*)&Cs[nl][mseg + s2 * 8];
            *(uint4*)&C2[(size_t)(n0 - 2048 + nl) * 4096 + m0 + c * 64 + mseg + s2 * 8] = v4;
          }
        }
        __syncthreads();
      }
      return;
    }
  }

#pragma unroll
  for (int i = 0; i < 4; ++i)
#pragma unroll
    for (int j = 0; j < 4; ++j)
#pragma unroll
      for (int r = 0; r < 4; ++r) {
        int m = m0 + wm + i * 16 + quad * 4 + r;
        int n = n0 + wn + j * 16 + ln;
        if constexpr (COUT_F32)
          ((float*)C)[(size_t)m * ldc + n] = acc[i][j][r];
        else
          ((u16*)C)[(size_t)m * ldc + n] = f2bf(acc[i][j][r]);
      }
}

// ---------------------------------------------------------------------------
// Causal flash attention (MFMA), fixed-base softmax, Q-tile = 128 rows/block
// (each wave owns 2 strips of 16 rows; K/V fragments shared across strips).
// K-tile 64, register-prefetch double-buffered LDS (padded stride 40 = 2-way
// free), one barrier/iter. Grid 512 linear: blocks c and c+256 are
// complementary (qt, 31-qt) of the SAME head -> co-resident pairs have
// constant total work (68 iters) and shared K/V L2 locality.
// ---------------------------------------------------------------------------
struct StageRegs { uint4 k0, k1, v0, v1; };

__device__ __forceinline__ StageRegs attn_stage_load(
    const u16* __restrict__ qk, const u16* __restrict__ vT,
    int h, int kbase, int tid) {
  StageRegs s;
  {
    int key = tid >> 2, seg = (tid & 3) * 16;
    const u16* kp = qk + (size_t)(kbase + key) * 2048 + 1024 + h * 64 + seg;
    s.k0 = *(const uint4*)kp;
    s.k1 = *(const uint4*)(kp + 8);
  }
  {
    int kh = tid >> 7, d = (tid >> 1) & 63, sg = (tid & 1) * 16;
    const u16* vp = vT + (size_t)(h * 64 + d) * 4096 + kbase + kh * 32 + sg;
    s.v0 = *(const uint4*)vp;
    s.v1 = *(const uint4*)(vp + 8);
  }
  return s;
}

__global__ __launch_bounds__(256, 2) void attn_fwd(
    const u16* __restrict__ qk, const u16* __restrict__ vT, u16* __restrict__ y)
{
  __shared__ u16 Ks[2][2][64][40];     // [buf][d-half][key][d%32] pad 40
  __shared__ u16 Vt[2][2][64][40];     // [buf][pi-key-half][d][pos%32]
  __shared__ u16 Ps[4][2][2][16][36];  // [wave][strip][half][row][pi-pos]

  const int tid  = threadIdx.x;
  const int wave = tid >> 6, lane = tid & 63;
  const int quad = lane >> 4, ln = lane & 15;
  const int bx = blockIdx.x;
  const int qt = (bx < 256) ? (31 - (bx >> 4)) : ((bx - 256) >> 4);
  const int h  = bx & 15;
  const float C1 = 0.18033688f;        // 0.125 * log2(e)

  const int sq0[2] = { qt * 128 + wave * 32, qt * 128 + wave * 32 + 16 };

  // Q strips (16 x 64 each): A[m=ln][k=quad*8+j], two 32-wide k halves
  bf16x8 qa[2][2];
#pragma unroll
  for (int s = 0; s < 2; ++s) {
    const u16* qrow = qk + (size_t)(sq0[s] + ln) * 2048 + h * 64;
    qa[s][0] = *(const bf16x8*)(qrow + quad * 8);
    qa[s][1] = *(const bf16x8*)(qrow + 32 + quad * 8);
  }

  f32x4 o[2][4] = {};
  float l_i[2][4] = {};

  StageRegs st = attn_stage_load(qk, vT, h, 0, tid);
  const int ktmax = 2 * qt + 1;
  int b = 0;
  for (int kt = 0; kt <= ktmax; ++kt, b ^= 1) {
    // write staged regs -> LDS buf b
    {
      int key = tid >> 2, seg = (tid & 3) * 16;
      int kh = seg >> 5, off = seg & 31;
      *(uint4*)&Ks[b][kh][key][off]     = st.k0;
      *(uint4*)&Ks[b][kh][key][off + 8] = st.k1;
      int vh = tid >> 7, d = (tid >> 1) & 63, sg = (tid & 1) * 16;
      *(uint4*)&Vt[b][vh][d][sg]     = st.v0;
      *(uint4*)&Vt[b][vh][d][sg + 8] = st.v1;
    }
    __syncthreads();
    if (kt < ktmax) st = attn_stage_load(qk, vT, h, (kt + 1) * 64, tid);

    // K / V fragments (shared by both strips)
    bf16x8 kf[2][4], vb[2][4];
#pragma unroll
    for (int hf = 0; hf < 2; ++hf)
#pragma unroll
      for (int c = 0; c < 4; ++c) {
        kf[hf][c] = *(const bf16x8*)&Ks[b][hf][c * 16 + ln][quad * 8];
        vb[hf][c] = *(const bf16x8*)&Vt[b][hf][c * 16 + ln][quad * 8];
      }

    bool act[2];
#pragma unroll
    for (int s = 0; s < 2; ++s) act[s] = (kt * 64 <= sq0[s] + 15);

#pragma unroll
    for (int s = 0; s < 2; ++s) {
      if (!act[s]) continue;           // wave-uniform
      f32x4 sv[4];
#pragma unroll
      for (int c = 0; c < 4; ++c) {
        f32x4 z = {0.f, 0.f, 0.f, 0.f};
        z = __builtin_amdgcn_mfma_f32_16x16x32_bf16(qa[s][0], kf[0][c], z, 0, 0, 0);
        z = __builtin_amdgcn_mfma_f32_16x16x32_bf16(qa[s][1], kf[1][c], z, 0, 0, 0);
        sv[c] = z;
      }
      float p[4][4];   // [c][r]
      if (kt * 64 + 63 > sq0[s]) {     // diagonal tile: per-element causal mask
        const int rowb = sq0[s] + quad * 4;
#pragma unroll
        for (int c = 0; c < 4; ++c) {
          int col = kt * 64 + c * 16 + ln;
#pragma unroll
          for (int r = 0; r < 4; ++r) {
            float arg = (col > rowb + r) ? -200.0f : fmaf(sv[c][r], C1, -46.0f);
            p[c][r] = fexp2(arg);
          }
        }
      } else {                          // full tile
#pragma unroll
        for (int c = 0; c < 4; ++c)
#pragma unroll
          for (int r = 0; r < 4; ++r)
            p[c][r] = fexp2(fmaf(sv[c][r], C1, -46.0f));
      }
#pragma unroll
      for (int r = 0; r < 4; ++r)
        l_i[s][r] += (p[0][r] + p[1][r]) + (p[2][r] + p[3][r]);
      // pack P (pi order) -> per-wave relay
#pragma unroll
      for (int r = 0; r < 4; ++r)
#pragma unroll
        for (int H = 0; H < 2; ++H)
          *(unsigned*)&Ps[wave][s][H][quad * 4 + r][ln * 2] = pkbf(p[2 * H][r], p[2 * H + 1][r]);
    }

    __asm__ volatile("s_waitcnt lgkmcnt(0)" ::: "memory");  // wave-local relay
#pragma unroll
    for (int s = 0; s < 2; ++s) {
      if (!act[s]) continue;
      bf16x8 pa0 = *(const bf16x8*)&Ps[wave][s][0][ln][quad * 8];
      bf16x8 pa1 = *(const bf16x8*)&Ps[wave][s][1][ln][quad * 8];
#pragma unroll
      for (int dt = 0; dt < 4; ++dt) {
        f32x4 z = o[s][dt];
        z = __builtin_amdgcn_mfma_f32_16x16x32_bf16(pa0, vb[0][dt], z, 0, 0, 0);
        z = __builtin_amdgcn_mfma_f32_16x16x32_bf16(pa1, vb[1][dt], z, 0, 0, 0);
        o[s][dt] = z;
      }
    }
  }

  // epilogue: deferred l reduction + normalized store, per strip
#pragma unroll
  for (int s = 0; s < 2; ++s) {
#pragma unroll
    for (int r = 0; r < 4; ++r) {
#pragma unroll
      for (int off = 8; off > 0; off >>= 1) l_i[s][r] += __shfl_xor(l_i[s][r], off, 16);
    }
#pragma unroll
    for (int r = 0; r < 4; ++r) {
      float inv = 1.0f / l_i[s][r];
      int rowg = sq0[s] + quad * 4 + r;
#pragma unroll
      for (int dt = 0; dt < 4; ++dt)
        y[(size_t)rowg * 1024 + h * 64 + dt * 16 + ln] = f2bf(o[s][dt][r] * inv);
    }
  }
}

extern "C" void kernel_launch(void* const* d_in, const int* in_sizes, int n_in,
                              void* d_out, int out_size, void* d_ws, size_t ws_size,
                              hipStream_t stream) {
  const float* x      = (const float*)d_in[0];   // [4096,1024] fp32
  const float* w_attn = (const float*)d_in[1];   // [3072,1024] fp32
  const float* w_proj = (const float*)d_in[2];   // [1024,1024] fp32

  char* ws = (char*)d_ws;
  u16* qk = (u16*)ws;                        // 16 MiB [4096][2048]
  u16* vT = (u16*)(ws + (16u << 20));        //  8 MiB [1024][4096] pi-permuted

  if (ws_size >= (size_t)(40u << 20)) {
    u16* wpb = (u16*)(ws + (24u << 20));     //  2 MiB bf16 w_proj
    u16* xb  = (u16*)(ws + (26u << 20));     //  8 MiB bf16 x   (dead after GEMM1)
    u16* wab = (u16*)(ws + (34u << 20));     //  6 MiB bf16 w_attn (dead after GEMM1)
    u16* y   = (u16*)(ws + (26u << 20));     //  8 MiB, overlays xb (lifetime-disjoint)

    cvt3<<<4096, 256, 0, stream>>>(x, w_attn, w_proj, xb, wab, wpb);
    gemm_lds<false, true><<<dim3(24, 32), 256, 0, stream>>>(
        xb, wab, qk, vT, 4096, 3072, 1024, 2048);
    attn_fwd<<<dim3(512), 256, 0, stream>>>(qk, vT, y);
    gemm_lds<true, false><<<dim3(8, 32), 256, 0, stream>>>(
        y, wpb, d_out, nullptr, 4096, 1024, 1024, 1024);
  } else {
    u16* y = (u16*)(ws + (24u << 20));
    gemm_bt<true, true, false, true><<<dim3(24, 32), 256, 0, stream>>>(
        x, w_attn, qk, vT, 4096, 3072, 1024, 2048);
    attn_fwd<<<dim3(512), 256, 0, stream>>>(qk, vT, y);
    gemm_bt<false, true, true, false><<<dim3(8, 32), 256, 0, stream>>>(
        y, w_proj, d_out, nullptr, 4096, 1024, 1024, 1024);
  }
}

// Round 10
// 210.346 us; speedup vs baseline: 1.1663x; 1.0355x over previous
//
#include <hip/hip_runtime.h>

typedef unsigned short u16;
typedef __bf16 bf16x8 __attribute__((ext_vector_type(8)));
typedef float f32x4 __attribute__((ext_vector_type(4)));

// fp32 -> bf16 bits, round-to-nearest-even (finite inputs only)
__device__ __forceinline__ u16 f2bf(float f) {
  union { float f; unsigned u; } v; v.f = f;
  return (u16)((v.u + 0x7fffu + ((v.u >> 16) & 1u)) >> 16);
}

// pack two fp32 -> bf16x2 dword (round-half-up), low = lo, high = hi
__device__ __forceinline__ unsigned pkbf(float lo, float hi) {
  union { float f; unsigned u; } a, b; a.f = lo; b.f = hi;
  return __builtin_amdgcn_perm(b.u + 0x8000u, a.u + 0x8000u, 0x07060302u);
}

__device__ __forceinline__ float fexp2(float x) {
#if __has_builtin(__builtin_amdgcn_exp2f)
  return __builtin_amdgcn_exp2f(x);
#else
  return exp2f(x);
#endif
}

// async global->LDS, 16B per lane; LDS dst = base + lane*16 (wave-uniform base)
__device__ __forceinline__ void gld16(const u16* g, u16* l) {
  __builtin_amdgcn_global_load_lds(
      (const __attribute__((address_space(1))) void*)g,
      (__attribute__((address_space(3))) void*)l, 16, 0, 0);
}

// pi permutation of a key k in [0,64) -> position in vT 64-block / P^T k-slot:
// pos = (k&32) + ((k>>2)&3)*8 + ((k>>4)&1)*4 + (k&3)
// (B-frag k-slot quad*8+j of half H holds key 32H + 16*(j>>2) + quad*4 + (j&3))

// ---------------------------------------------------------------------------
// fp32 -> bf16 bulk convert for all three inputs in ONE dispatch.
// ---------------------------------------------------------------------------
__global__ __launch_bounds__(256) void cvt3(
    const float* __restrict__ x, const float* __restrict__ wa,
    const float* __restrict__ wp, u16* __restrict__ xb,
    u16* __restrict__ wab, u16* __restrict__ wpb)
{
  int b = blockIdx.x;
  const float* in; u16* out; int i;
  if (b < 2048)      { in = x;  out = xb;  i = b * 256 + threadIdx.x; }
  else if (b < 3584) { in = wa; out = wab; i = (b - 2048) * 256 + threadIdx.x; }
  else               { in = wp; out = wpb; i = (b - 3584) * 256 + threadIdx.x; }
  const float* p = in + (size_t)i * 8;
  float4 a = *(const float4*)p, c = *(const float4*)(p + 4);
  uint4 o;
  o.x = pkbf(a.x, a.y); o.y = pkbf(a.z, a.w);
  o.z = pkbf(c.x, c.y); o.w = pkbf(c.z, c.w);
  *(uint4*)&out[(size_t)i * 8] = o;
}

// ---------------------------------------------------------------------------
// m97-style GEMM: C[M,N] = A[M,K]*B[N,K]^T, bf16 in, fp32 acc.
// VSPLIT: n0>=2048 blocks write V TRANSPOSED to C2 (vT[1024][4096]) in
// pi-permuted key order (see pi above).
// ---------------------------------------------------------------------------
template<bool COUT_F32, bool VSPLIT>
__global__ __launch_bounds__(256, 3) void gemm_lds(
    const u16* __restrict__ A, const u16* __restrict__ B, void* __restrict__ C,
    u16* __restrict__ C2, int M, int N, int K, int ldc)
{
  __shared__ u16 S[9216];
  u16* As = S;
  u16* Bs = S + 4096;
  const int tid  = threadIdx.x;
  const int wave = tid >> 6, lane = tid & 63;
  const int quad = lane >> 4, ln = lane & 15;
  const int m0 = blockIdx.y * 128, n0 = blockIdx.x * 128;
  const int wm = (wave >> 1) * 64, wn = (wave & 1) * 64;

  const int srow = wave * 32 + (lane >> 2);
  const int scol = (lane & 3) * 8;

  f32x4 acc[4][4] = {};

  for (int k0 = 0; k0 < K; k0 += 32) {
    __syncthreads();
    const u16* ga = A + (size_t)(m0 + srow) * K + k0 + scol;
    const u16* gb = B + (size_t)(n0 + srow) * K + k0 + scol;
    gld16(ga,                  As + wave * 1024);
    gld16(ga + (size_t)16 * K, As + wave * 1024 + 512);
    gld16(gb,                  Bs + wave * 1024);
    gld16(gb + (size_t)16 * K, Bs + wave * 1024 + 512);
    __syncthreads();

    bf16x8 af[4], bfr[4];
#pragma unroll
    for (int i = 0; i < 4; ++i) af[i]  = *(const bf16x8*)&As[(wm + i * 16 + ln) * 32 + quad * 8];
#pragma unroll
    for (int j = 0; j < 4; ++j) bfr[j] = *(const bf16x8*)&Bs[(wn + j * 16 + ln) * 32 + quad * 8];
#pragma unroll
    for (int i = 0; i < 4; ++i)
#pragma unroll
      for (int j = 0; j < 4; ++j)
        acc[i][j] = __builtin_amdgcn_mfma_f32_16x16x32_bf16(af[i], bfr[j], acc[i][j], 0, 0, 0);
  }

  if constexpr (VSPLIT) {
    if (n0 >= 2048) {
      u16 (*Cs)[72] = (u16(*)[72])S;
      __syncthreads();
#pragma unroll
      for (int c = 0; c < 2; ++c) {
        if ((wave >> 1) == c) {
#pragma unroll
          for (int i = 0; i < 4; ++i)
#pragma unroll
            for (int j = 0; j < 4; ++j)
#pragma unroll
              for (int r = 0; r < 4; ++r) {
                // m-in-chunk = i*16+quad*4+r; pi pos = (i>>1)*32 + quad*8 + (i&1)*4 + r
                int pos = (i >> 1) * 32 + quad * 8 + (i & 1) * 4 + r;
                Cs[wn + j * 16 + ln][pos] = f2bf(acc[i][j][r]);
              }
        }
        __syncthreads();
        {
          int nl = tid >> 1, mseg = (tid & 1) * 32;
#pragma unroll
          for (int s2 = 0; s2 < 4; ++s2) {
            uint4 v4 = *(const uint4*)&Cs[nl][mseg + s2 * 8];
            *(uint4*)&C2[(size_t)(n0 - 2048 + nl) * 4096 + m0 + c * 64 + mseg + s2 * 8] = v4;
          }
        }
        __syncthreads();
      }
      return;
    }
  }

#pragma unroll
  for (int i = 0; i < 4; ++i)
#pragma unroll
    for (int j = 0; j < 4; ++j)
#pragma unroll
      for (int r = 0; r < 4; ++r) {
        int m = m0 + wm + i * 16 + quad * 4 + r;   // C/D: row = quad*4+reg
        int n = n0 + wn + j * 16 + ln;             //      col = lane&15
        if constexpr (COUT_F32)
          ((float*)C)[(size_t)m * ldc + n] = acc[i][j][r];
        else
          ((u16*)C)[(size_t)m * ldc + n] = f2bf(acc[i][j][r]);
      }
}

// ---------------------------------------------------------------------------
// 128x64-tile GEMM for GEMM2 (N=1024): grid 16x32 = 512 blocks (2/CU).
// Each wave: 4x2 acc tiles. Same gld16 staging recipe.
// ---------------------------------------------------------------------------
template<bool COUT_F32>
__global__ __launch_bounds__(256, 2) void gemm_n64(
    const u16* __restrict__ A, const u16* __restrict__ B, void* __restrict__ C,
    int M, int N, int K, int ldc)
{
  __shared__ u16 S[6144];            // As[128][32]@0, Bs[64][32]@4096
  u16* As = S;
  u16* Bs = S + 4096;
  const int tid  = threadIdx.x;
  const int wave = tid >> 6, lane = tid & 63;
  const int quad = lane >> 4, ln = lane & 15;
  const int m0 = blockIdx.y * 128, n0 = blockIdx.x * 64;
  const int wm = (wave >> 1) * 64, wn = (wave & 1) * 32;

  const int srowA = wave * 32 + (lane >> 2);
  const int srowB = wave * 16 + (lane >> 2);
  const int scol  = (lane & 3) * 8;

  f32x4 acc[4][2] = {};

  for (int k0 = 0; k0 < K; k0 += 32) {
    __syncthreads();
    const u16* ga = A + (size_t)(m0 + srowA) * K + k0 + scol;
    const u16* gb = B + (size_t)(n0 + srowB) * K + k0 + scol;
    gld16(ga,                  As + wave * 1024);
    gld16(ga + (size_t)16 * K, As + wave * 1024 + 512);
    gld16(gb,                  Bs + wave * 512);
    __syncthreads();

    bf16x8 af[4], bfr[2];
#pragma unroll
    for (int i = 0; i < 4; ++i) af[i]  = *(const bf16x8*)&As[(wm + i * 16 + ln) * 32 + quad * 8];
#pragma unroll
    for (int j = 0; j < 2; ++j) bfr[j] = *(const bf16x8*)&Bs[(wn + j * 16 + ln) * 32 + quad * 8];
#pragma unroll
    for (int i = 0; i < 4; ++i)
#pragma unroll
      for (int j = 0; j < 2; ++j)
        acc[i][j] = __builtin_amdgcn_mfma_f32_16x16x32_bf16(af[i], bfr[j], acc[i][j], 0, 0, 0);
  }

#pragma unroll
  for (int i = 0; i < 4; ++i)
#pragma unroll
    for (int j = 0; j < 2; ++j)
#pragma unroll
      for (int r = 0; r < 4; ++r) {
        int m = m0 + wm + i * 16 + quad * 4 + r;
        int n = n0 + wn + j * 16 + ln;
        if constexpr (COUT_F32)
          ((float*)C)[(size_t)m * ldc + n] = acc[i][j][r];
        else
          ((u16*)C)[(size_t)m * ldc + n] = f2bf(acc[i][j][r]);
      }
}

// ---------------------------------------------------------------------------
// Fallback GEMM (fp32 staging) — used only if ws_size < 40 MiB.
// ---------------------------------------------------------------------------
template<bool F32>
__device__ __forceinline__ void stage8(u16* dst, const void* base, size_t off) {
  if constexpr (F32) {
    const float* p = (const float*)base + off;
    float4 a = *(const float4*)p;
    float4 b = *(const float4*)(p + 4);
    uint4 q;
    q.x = pkbf(a.x, a.y); q.y = pkbf(a.z, a.w);
    q.z = pkbf(b.x, b.y); q.w = pkbf(b.z, b.w);
    *(uint4*)dst = q;
  } else {
    *(uint4*)dst = *(const uint4*)((const u16*)base + off);
  }
}

template<bool AF32, bool BF32, bool COUT_F32, bool VSPLIT>
__global__ __launch_bounds__(256) void gemm_bt(
    const void* __restrict__ A, const void* __restrict__ B, void* __restrict__ C,
    u16* __restrict__ C2, int M, int N, int K, int ldc)
{
  __shared__ u16 As[128][40];
  __shared__ u16 Bs[128][40];
  const int tid  = threadIdx.x;
  const int wave = tid >> 6, lane = tid & 63;
  const int quad = lane >> 4, ln = lane & 15;
  const int m0 = blockIdx.y * 128, n0 = blockIdx.x * 128;
  const int wm = (wave >> 1) * 64, wn = (wave & 1) * 64;

  f32x4 acc[4][4] = {};

  for (int k0 = 0; k0 < K; k0 += 32) {
    __syncthreads();
#pragma unroll
    for (int i = 0; i < 2; ++i) {
      int idx = tid + i * 256;
      int row = idx >> 2, seg = (idx & 3) * 8;
      stage8<AF32>(&As[row][seg], A, (size_t)(m0 + row) * K + k0 + seg);
      stage8<BF32>(&Bs[row][seg], B, (size_t)(n0 + row) * K + k0 + seg);
    }
    __syncthreads();
    bf16x8 af[4], bfr[4];
#pragma unroll
    for (int i = 0; i < 4; ++i) af[i]  = *(const bf16x8*)&As[wm + i * 16 + ln][quad * 8];
#pragma unroll
    for (int j = 0; j < 4; ++j) bfr[j] = *(const bf16x8*)&Bs[wn + j * 16 + ln][quad * 8];
#pragma unroll
    for (int i = 0; i < 4; ++i)
#pragma unroll
      for (int j = 0; j < 4; ++j)
        acc[i][j] = __builtin_amdgcn_mfma_f32_16x16x32_bf16(af[i], bfr[j], acc[i][j], 0, 0, 0);
  }

  if constexpr (VSPLIT) {
    if (n0 >= 2048) {
      __shared__ u16 Cs[128][72];
#pragma unroll
      for (int c = 0; c < 2; ++c) {
        if ((wave >> 1) == c) {
#pragma unroll
          for (int i = 0; i < 4; ++i)
#pragma unroll
            for (int j = 0; j < 4; ++j)
#pragma unroll
              for (int r = 0; r < 4; ++r) {
                int pos = (i >> 1) * 32 + quad * 8 + (i & 1) * 4 + r;
                Cs[wn + j * 16 + ln][pos] = f2bf(acc[i][j][r]);
              }
        }
        __syncthreads();
        {
          int nl = tid >> 1, mseg = (tid & 1) * 32;
#pragma unroll
          for (int s2 = 0; s2 < 4; ++s2) {
            uint4 v4 = *(const uint4*)&Cs[nl][mseg + s2 * 8];
            *(uint4*)&C2[(size_t)(n0 - 2048 + nl) * 4096 + m0 + c * 64 + mseg + s2 * 8] = v4;
          }
        }
        __syncthreads();
      }
      return;
    }
  }

#pragma unroll
  for (int i = 0; i < 4; ++i)
#pragma unroll
    for (int j = 0; j < 4; ++j)
#pragma unroll
      for (int r = 0; r < 4; ++r) {
        int m = m0 + wm + i * 16 + quad * 4 + r;
        int n = n0 + wn + j * 16 + ln;
        if constexpr (COUT_F32)
          ((float*)C)[(size_t)m * ldc + n] = acc[i][j][r];
        else
          ((u16*)C)[(size_t)m * ldc + n] = f2bf(acc[i][j][r]);
      }
}

// ---------------------------------------------------------------------------
// Causal flash attention (MFMA), fixed-base softmax, TRANSPOSED score path:
// S^T = K·Q^T  (mfma(kf,qa) — same regs as before, swapped operands), so
// C-layout gives col=qrow=ln, row=key=quad*4+r. P^T is then directly a
// B-operand fragment built IN-REGISTER (no LDS relay, no lgkm wait):
// O^T = V^T·P^T with A = V^T (d-major in LDS, pi-permuted keys).
// Q-tile 128 (2 strips/wave), K-tile 64, register-prefetch double buffer.
// LDS 40 KB. Grid 512 (32 qt x 16 h), heavy-first.
// ---------------------------------------------------------------------------
struct StageRegs { uint4 k0, k1, v0, v1; };

__device__ __forceinline__ StageRegs attn_stage_load(
    const u16* __restrict__ qk, const u16* __restrict__ vT,
    int h, int kbase, int tid) {
  StageRegs s;
  {
    int key = tid >> 2, seg = (tid & 3) * 16;
    const u16* kp = qk + (size_t)(kbase + key) * 2048 + 1024 + h * 64 + seg;
    s.k0 = *(const uint4*)kp;
    s.k1 = *(const uint4*)(kp + 8);
  }
  {
    int kh = tid >> 7, d = (tid >> 1) & 63, sg = (tid & 1) * 16;
    const u16* vp = vT + (size_t)(h * 64 + d) * 4096 + kbase + kh * 32 + sg;
    s.v0 = *(const uint4*)vp;
    s.v1 = *(const uint4*)(vp + 8);
  }
  return s;
}

__global__ __launch_bounds__(256, 2) void attn_fwd(
    const u16* __restrict__ qk, const u16* __restrict__ vT, u16* __restrict__ y)
{
  __shared__ u16 Ks[2][2][64][40];     // [buf][d-half][key][d%32] pad 40
  __shared__ u16 Vt[2][2][64][40];     // [buf][pi-key-half][d][pos%32]

  const int tid  = threadIdx.x;
  const int wave = tid >> 6, lane = tid & 63;
  const int quad = lane >> 4, ln = lane & 15;
  const int bx = blockIdx.x;
  const int qt = 31 - (bx >> 4);       // heavy first
  const int h  = bx & 15;
  const float C1 = 0.18033688f;        // 0.125 * log2(e)

  const int sq0[2] = { qt * 128 + wave * 32, qt * 128 + wave * 32 + 16 };

  // Q strips (16 x 64 each): lane holds qrow=ln, d=quad*8+j per 32-half
  // (serves as B-operand of S^T = K·Q^T)
  bf16x8 qa[2][2];
#pragma unroll
  for (int s = 0; s < 2; ++s) {
    const u16* qrow = qk + (size_t)(sq0[s] + ln) * 2048 + h * 64;
    qa[s][0] = *(const bf16x8*)(qrow + quad * 8);
    qa[s][1] = *(const bf16x8*)(qrow + 32 + quad * 8);
  }

  f32x4 o[2][4] = {};                  // O^T tiles: [strip][d-tile]; row=d, col=qrow
  float l_i[2] = {0.f, 0.f};           // per-lane partial l for qrow=ln

  StageRegs st = attn_stage_load(qk, vT, h, 0, tid);
  const int ktmax = 2 * qt + 1;
  int b = 0;
  for (int kt = 0; kt <= ktmax; ++kt, b ^= 1) {
    {
      int key = tid >> 2, seg = (tid & 3) * 16;
      int kh = seg >> 5, off = seg & 31;
      *(uint4*)&Ks[b][kh][key][off]     = st.k0;
      *(uint4*)&Ks[b][kh][key][off + 8] = st.k1;
      int vh = tid >> 7, d = (tid >> 1) & 63, sg = (tid & 1) * 16;
      *(uint4*)&Vt[b][vh][d][sg]     = st.v0;
      *(uint4*)&Vt[b][vh][d][sg + 8] = st.v1;
    }
    __syncthreads();
    if (kt < ktmax) st = attn_stage_load(qk, vT, h, (kt + 1) * 64, tid);

    // K-frags (A-op of S^T: lane m=key=ln) and V^T-frags (A-op of O^T: lane m=d=ln)
    bf16x8 kf[2][4], vb[2][4];
#pragma unroll
    for (int hf = 0; hf < 2; ++hf)
#pragma unroll
      for (int c = 0; c < 4; ++c) {
        kf[hf][c] = *(const bf16x8*)&Ks[b][hf][c * 16 + ln][quad * 8];
        vb[hf][c] = *(const bf16x8*)&Vt[b][hf][c * 16 + ln][quad * 8];
      }

    bool act[2];
#pragma unroll
    for (int s = 0; s < 2; ++s) act[s] = (kt * 64 <= sq0[s] + 15);

    bf16x8 pb[2][2];                   // [strip][half] P^T B-frags
#pragma unroll
    for (int s = 0; s < 2; ++s) {
      if (!act[s]) continue;           // wave-uniform
      // S^T (64 keys x 16 qrows): 4 key-tiles t, contraction d=64
      f32x4 sv[4];
#pragma unroll
      for (int t = 0; t < 4; ++t) {
        f32x4 z = {0.f, 0.f, 0.f, 0.f};
        z = __builtin_amdgcn_mfma_f32_16x16x32_bf16(kf[0][t], qa[s][0], z, 0, 0, 0);
        z = __builtin_amdgcn_mfma_f32_16x16x32_bf16(kf[1][t], qa[s][1], z, 0, 0, 0);
        sv[t] = z;                     // row=key=t*16+quad*4+r, col=qrow=ln
      }
      float p[4][4];                   // [t][r]
      if (kt * 64 + 63 > sq0[s]) {     // diagonal region: per-element causal mask
        const int qr = sq0[s] + ln;
#pragma unroll
        for (int t = 0; t < 4; ++t) {
          int keyb = kt * 64 + t * 16 + quad * 4;
#pragma unroll
          for (int r = 0; r < 4; ++r) {
            float arg = (keyb + r > qr) ? -200.0f : fmaf(sv[t][r], C1, -46.0f);
            p[t][r] = fexp2(arg);
          }
        }
      } else {
#pragma unroll
        for (int t = 0; t < 4; ++t)
#pragma unroll
          for (int r = 0; r < 4; ++r)
            p[t][r] = fexp2(fmaf(sv[t][r], C1, -46.0f));
      }
#pragma unroll
      for (int t = 0; t < 4; ++t)
        l_i[s] += (p[t][0] + p[t][1]) + (p[t][2] + p[t][3]);
      // build P^T B-frags in-register: half H slot j<4 -> p[2H][j], j>=4 -> p[2H+1][j-4]
#pragma unroll
      for (int H = 0; H < 2; ++H) {
        union { unsigned u[4]; bf16x8 v; } pk;
        pk.u[0] = pkbf(p[2 * H][0],     p[2 * H][1]);
        pk.u[1] = pkbf(p[2 * H][2],     p[2 * H][3]);
        pk.u[2] = pkbf(p[2 * H + 1][0], p[2 * H + 1][1]);
        pk.u[3] = pkbf(p[2 * H + 1][2], p[2 * H + 1][3]);
        pb[s][H] = pk.v;
      }
    }

    // O^T += V^T · P^T  (no waits: all operands in registers)
#pragma unroll
    for (int s = 0; s < 2; ++s) {
      if (!act[s]) continue;
#pragma unroll
      for (int dt = 0; dt < 4; ++dt) {
        f32x4 z = o[s][dt];
        z = __builtin_amdgcn_mfma_f32_16x16x32_bf16(vb[0][dt], pb[s][0], z, 0, 0, 0);
        z = __builtin_amdgcn_mfma_f32_16x16x32_bf16(vb[1][dt], pb[s][1], z, 0, 0, 0);
        o[s][dt] = z;
      }
    }
  }

  // deferred l reduction across the 4 quads holding the same qrow=ln
#pragma unroll
  for (int s = 0; s < 2; ++s) {
    l_i[s] += __shfl_xor(l_i[s], 16);
    l_i[s] += __shfl_xor(l_i[s], 32);
    float inv = 1.0f / l_i[s];
    int rowg = sq0[s] + ln;
#pragma unroll
    for (int dt = 0; dt < 4; ++dt)
#pragma unroll
      for (int r = 0; r < 4; ++r)
        y[(size_t)rowg * 1024 + h * 64 + dt * 16 + quad * 4 + r] = f2bf(o[s][dt][r] * inv);
  }
}

extern "C" void kernel_launch(void* const* d_in, const int* in_sizes, int n_in,
                              void* d_out, int out_size, void* d_ws, size_t ws_size,
                              hipStream_t stream) {
  const float* x      = (const float*)d_in[0];   // [4096,1024] fp32
  const float* w_attn = (const float*)d_in[1];   // [3072,1024] fp32
  const float* w_proj = (const float*)d_in[2];   // [1024,1024] fp32

  char* ws = (char*)d_ws;
  u16* qk = (u16*)ws;                        // 16 MiB [4096][2048]
  u16* vT = (u16*)(ws + (16u << 20));        //  8 MiB [1024][4096] pi-permuted

  if (ws_size >= (size_t)(40u << 20)) {
    u16* wpb = (u16*)(ws + (24u << 20));     //  2 MiB bf16 w_proj
    u16* xb  = (u16*)(ws + (26u << 20));     //  8 MiB bf16 x   (dead after GEMM1)
    u16* wab = (u16*)(ws + (34u << 20));     //  6 MiB bf16 w_attn (dead after GEMM1)
    u16* y   = (u16*)(ws + (26u << 20));     //  8 MiB, overlays xb (lifetime-disjoint)

    cvt3<<<4096, 256, 0, stream>>>(x, w_attn, w_proj, xb, wab, wpb);
    gemm_lds<false, true><<<dim3(24, 32), 256, 0, stream>>>(
        xb, wab, qk, vT, 4096, 3072, 1024, 2048);
    attn_fwd<<<dim3(512), 256, 0, stream>>>(qk, vT, y);
    gemm_n64<true><<<dim3(16, 32), 256, 0, stream>>>(
        y, wpb, d_out, 4096, 1024, 1024, 1024);
  } else {
    u16* y = (u16*)(ws + (24u << 20));
    gemm_bt<true, true, false, true><<<dim3(24, 32), 256, 0, stream>>>(
        x, w_attn, qk, vT, 4096, 3072, 1024, 2048);
    attn_fwd<<<dim3(512), 256, 0, stream>>>(qk, vT, y);
    gemm_bt<false, true, true, false><<<dim3(8, 32), 256, 0, stream>>>(
        y, w_proj, d_out, nullptr, 4096, 1024, 1024, 1024);
  }
}

// Round 11
// 204.894 us; speedup vs baseline: 1.1974x; 1.0266x over previous
//
#include <hip/hip_runtime.h>

typedef unsigned short u16;
typedef __bf16 bf16x8 __attribute__((ext_vector_type(8)));
typedef float f32x4 __attribute__((ext_vector_type(4)));

// fp32 -> bf16 bits, round-to-nearest-even (finite inputs only)
__device__ __forceinline__ u16 f2bf(float f) {
  union { float f; unsigned u; } v; v.f = f;
  return (u16)((v.u + 0x7fffu + ((v.u >> 16) & 1u)) >> 16);
}

// pack two fp32 -> bf16x2 dword (round-half-up), low = lo, high = hi
__device__ __forceinline__ unsigned pkbf(float lo, float hi) {
  union { float f; unsigned u; } a, b; a.f = lo; b.f = hi;
  return __builtin_amdgcn_perm(b.u + 0x8000u, a.u + 0x8000u, 0x07060302u);
}

__device__ __forceinline__ float fexp2(float x) {
#if __has_builtin(__builtin_amdgcn_exp2f)
  return __builtin_amdgcn_exp2f(x);
#else
  return exp2f(x);
#endif
}

// async global->LDS, 16B per lane; LDS dst = base + lane*16 (wave-uniform base)
__device__ __forceinline__ void gld16(const u16* g, u16* l) {
  __builtin_amdgcn_global_load_lds(
      (const __attribute__((address_space(1))) void*)g,
      (__attribute__((address_space(3))) void*)l, 16, 0, 0);
}

// pi permutation of a key k in [0,64) -> position in vT 64-block / P^T k-slot:
// pos = (k&32) + ((k>>2)&3)*8 + ((k>>4)&1)*4 + (k&3)

// ---------------------------------------------------------------------------
// fp32 -> bf16 bulk convert for all three inputs in ONE dispatch.
// ---------------------------------------------------------------------------
__global__ __launch_bounds__(256) void cvt3(
    const float* __restrict__ x, const float* __restrict__ wa,
    const float* __restrict__ wp, u16* __restrict__ xb,
    u16* __restrict__ wab, u16* __restrict__ wpb)
{
  int b = blockIdx.x;
  const float* in; u16* out; int i;
  if (b < 2048)      { in = x;  out = xb;  i = b * 256 + threadIdx.x; }
  else if (b < 3584) { in = wa; out = wab; i = (b - 2048) * 256 + threadIdx.x; }
  else               { in = wp; out = wpb; i = (b - 3584) * 256 + threadIdx.x; }
  const float* p = in + (size_t)i * 8;
  float4 a = *(const float4*)p, c = *(const float4*)(p + 4);
  uint4 o;
  o.x = pkbf(a.x, a.y); o.y = pkbf(a.z, a.w);
  o.z = pkbf(c.x, c.y); o.w = pkbf(c.z, c.w);
  *(uint4*)&out[(size_t)i * 8] = o;
}

// ---------------------------------------------------------------------------
// m97-style GEMM: C[M,N] = A[M,K]*B[N,K]^T, bf16 in, fp32 acc.
// VSPLIT: n0>=2048 blocks write V TRANSPOSED to C2 (vT[1024][4096]) in
// pi-permuted key order.
// ---------------------------------------------------------------------------
template<bool COUT_F32, bool VSPLIT>
__global__ __launch_bounds__(256, 3) void gemm_lds(
    const u16* __restrict__ A, const u16* __restrict__ B, void* __restrict__ C,
    u16* __restrict__ C2, int M, int N, int K, int ldc)
{
  __shared__ u16 S[9216];
  u16* As = S;
  u16* Bs = S + 4096;
  const int tid  = threadIdx.x;
  const int wave = tid >> 6, lane = tid & 63;
  const int quad = lane >> 4, ln = lane & 15;
  const int m0 = blockIdx.y * 128, n0 = blockIdx.x * 128;
  const int wm = (wave >> 1) * 64, wn = (wave & 1) * 64;

  const int srow = wave * 32 + (lane >> 2);
  const int scol = (lane & 3) * 8;

  f32x4 acc[4][4] = {};

  for (int k0 = 0; k0 < K; k0 += 32) {
    __syncthreads();
    const u16* ga = A + (size_t)(m0 + srow) * K + k0 + scol;
    const u16* gb = B + (size_t)(n0 + srow) * K + k0 + scol;
    gld16(ga,                  As + wave * 1024);
    gld16(ga + (size_t)16 * K, As + wave * 1024 + 512);
    gld16(gb,                  Bs + wave * 1024);
    gld16(gb + (size_t)16 * K, Bs + wave * 1024 + 512);
    __syncthreads();

    bf16x8 af[4], bfr[4];
#pragma unroll
    for (int i = 0; i < 4; ++i) af[i]  = *(const bf16x8*)&As[(wm + i * 16 + ln) * 32 + quad * 8];
#pragma unroll
    for (int j = 0; j < 4; ++j) bfr[j] = *(const bf16x8*)&Bs[(wn + j * 16 + ln) * 32 + quad * 8];
#pragma unroll
    for (int i = 0; i < 4; ++i)
#pragma unroll
      for (int j = 0; j < 4; ++j)
        acc[i][j] = __builtin_amdgcn_mfma_f32_16x16x32_bf16(af[i], bfr[j], acc[i][j], 0, 0, 0);
  }

  if constexpr (VSPLIT) {
    if (n0 >= 2048) {
      u16 (*Cs)[72] = (u16(*)[72])S;
      __syncthreads();
#pragma unroll
      for (int c = 0; c < 2; ++c) {
        if ((wave >> 1) == c) {
#pragma unroll
          for (int i = 0; i < 4; ++i)
#pragma unroll
            for (int j = 0; j < 4; ++j)
#pragma unroll
              for (int r = 0; r < 4; ++r) {
                // m-in-chunk = i*16+quad*4+r; pi pos = (i>>1)*32 + quad*8 + (i&1)*4 + r
                int pos = (i >> 1) * 32 + quad * 8 + (i & 1) * 4 + r;
                Cs[wn + j * 16 + ln][pos] = f2bf(acc[i][j][r]);
              }
        }
        __syncthreads();
        {
          int nl = tid >> 1, mseg = (tid & 1) * 32;
#pragma unroll
          for (int s2 = 0; s2 < 4; ++s2) {
            uint4 v4 = *(const uint4*)&Cs[nl][mseg + s2 * 8];
            *(uint4*)&C2[(size_t)(n0 - 2048 + nl) * 4096 + m0 + c * 64 + mseg + s2 * 8] = v4;
          }
        }
        __syncthreads();
      }
      return;
    }
  }

#pragma unroll
  for (int i = 0; i < 4; ++i)
#pragma unroll
    for (int j = 0; j < 4; ++j)
#pragma unroll
      for (int r = 0; r < 4; ++r) {
        int m = m0 + wm + i * 16 + quad * 4 + r;   // C/D: row = quad*4+reg
        int n = n0 + wn + j * 16 + ln;             //      col = lane&15
        if constexpr (COUT_F32)
          ((float*)C)[(size_t)m * ldc + n] = acc[i][j][r];
        else
          ((u16*)C)[(size_t)m * ldc + n] = f2bf(acc[i][j][r]);
      }
}

// ---------------------------------------------------------------------------
// 64x64-tile GEMM for GEMM2 (latency-bound -> maximize blocks/CU):
// grid (N/64, M/64) = (16,64) = 1024 blocks = 4/CU. 8 KB LDS, ~64 VGPR.
// Wave w owns m-strip 16; 1x4 acc tiles; 2 gld16 issues/wave/iter.
// ---------------------------------------------------------------------------
template<bool COUT_F32>
__global__ __launch_bounds__(256, 4) void gemm_t64(
    const u16* __restrict__ A, const u16* __restrict__ B, void* __restrict__ C,
    int M, int N, int K, int ldc)
{
  __shared__ u16 S[4096];            // As[64][32]@0, Bs[64][32]@2048
  u16* As = S;
  u16* Bs = S + 2048;
  const int tid  = threadIdx.x;
  const int wave = tid >> 6, lane = tid & 63;
  const int quad = lane >> 4, ln = lane & 15;
  const int m0 = blockIdx.y * 64, n0 = blockIdx.x * 64;

  const int srow = wave * 16 + (lane >> 2);   // 16 rows per wave
  const int scol = (lane & 3) * 8;

  f32x4 acc[4] = {};

  for (int k0 = 0; k0 < K; k0 += 32) {
    __syncthreads();
    gld16(A + (size_t)(m0 + srow) * K + k0 + scol, As + wave * 512);
    gld16(B + (size_t)(n0 + srow) * K + k0 + scol, Bs + wave * 512);
    __syncthreads();

    bf16x8 af = *(const bf16x8*)&As[(wave * 16 + ln) * 32 + quad * 8];
#pragma unroll
    for (int j = 0; j < 4; ++j) {
      bf16x8 bf = *(const bf16x8*)&Bs[(j * 16 + ln) * 32 + quad * 8];
      acc[j] = __builtin_amdgcn_mfma_f32_16x16x32_bf16(af, bf, acc[j], 0, 0, 0);
    }
  }

#pragma unroll
  for (int j = 0; j < 4; ++j)
#pragma unroll
    for (int r = 0; r < 4; ++r) {
      int m = m0 + wave * 16 + quad * 4 + r;
      int n = n0 + j * 16 + ln;
      if constexpr (COUT_F32)
        ((float*)C)[(size_t)m * ldc + n] = acc[j][r];
      else
        ((u16*)C)[(size_t)m * ldc + n] = f2bf(acc[j][r]);
    }
}

// ---------------------------------------------------------------------------
// Fallback GEMM (fp32 staging) — used only if ws_size < 40 MiB.
// ---------------------------------------------------------------------------
template<bool F32>
__device__ __forceinline__ void stage8(u16* dst, const void* base, size_t off) {
  if constexpr (F32) {
    const float* p = (const float*)base + off;
    float4 a = *(const float4*)p;
    float4 b = *(const float4*)(p + 4);
    uint4 q;
    q.x = pkbf(a.x, a.y); q.y = pkbf(a.z, a.w);
    q.z = pkbf(b.x, b.y); q.w = pkbf(b.z, b.w);
    *(uint4*)dst = q;
  } else {
    *(uint4*)dst = *(const uint4*)((const u16*)base + off);
  }
}

template<bool AF32, bool BF32, bool COUT_F32, bool VSPLIT>
__global__ __launch_bounds__(256) void gemm_bt(
    const void* __restrict__ A, const void* __restrict__ B, void* __restrict__ C,
    u16* __restrict__ C2, int M, int N, int K, int ldc)
{
  __shared__ u16 As[128][40];
  __shared__ u16 Bs[128][40];
  const int tid  = threadIdx.x;
  const int wave = tid >> 6, lane = tid & 63;
  const int quad = lane >> 4, ln = lane & 15;
  const int m0 = blockIdx.y * 128, n0 = blockIdx.x * 128;
  const int wm = (wave >> 1) * 64, wn = (wave & 1) * 64;

  f32x4 acc[4][4] = {};

  for (int k0 = 0; k0 < K; k0 += 32) {
    __syncthreads();
#pragma unroll
    for (int i = 0; i < 2; ++i) {
      int idx = tid + i * 256;
      int row = idx >> 2, seg = (idx & 3) * 8;
      stage8<AF32>(&As[row][seg], A, (size_t)(m0 + row) * K + k0 + seg);
      stage8<BF32>(&Bs[row][seg], B, (size_t)(n0 + row) * K + k0 + seg);
    }
    __syncthreads();
    bf16x8 af[4], bfr[4];
#pragma unroll
    for (int i = 0; i < 4; ++i) af[i]  = *(const bf16x8*)&As[wm + i * 16 + ln][quad * 8];
#pragma unroll
    for (int j = 0; j < 4; ++j) bfr[j] = *(const bf16x8*)&Bs[wn + j * 16 + ln][quad * 8];
#pragma unroll
    for (int i = 0; i < 4; ++i)
#pragma unroll
      for (int j = 0; j < 4; ++j)
        acc[i][j] = __builtin_amdgcn_mfma_f32_16x16x32_bf16(af[i], bfr[j], acc[i][j], 0, 0, 0);
  }

  if constexpr (VSPLIT) {
    if (n0 >= 2048) {
      __shared__ u16 Cs[128][72];
#pragma unroll
      for (int c = 0; c < 2; ++c) {
        if ((wave >> 1) == c) {
#pragma unroll
          for (int i = 0; i < 4; ++i)
#pragma unroll
            for (int j = 0; j < 4; ++j)
#pragma unroll
              for (int r = 0; r < 4; ++r) {
                int pos = (i >> 1) * 32 + quad * 8 + (i & 1) * 4 + r;
                Cs[wn + j * 16 + ln][pos] = f2bf(acc[i][j][r]);
              }
        }
        __syncthreads();
        {
          int nl = tid >> 1, mseg = (tid & 1) * 32;
#pragma unroll
          for (int s2 = 0; s2 < 4; ++s2) {
            uint4 v4 = *(const uint4*)&Cs[nl][mseg + s2 * 8];
            *(uint4*)&C2[(size_t)(n0 - 2048 + nl) * 4096 + m0 + c * 64 + mseg + s2 * 8] = v4;
          }
        }
        __syncthreads();
      }
      return;
    }
  }

#pragma unroll
  for (int i = 0; i < 4; ++i)
#pragma unroll
    for (int j = 0; j < 4; ++j)
#pragma unroll
      for (int r = 0; r < 4; ++r) {
        int m = m0 + wm + i * 16 + quad * 4 + r;
        int n = n0 + wn + j * 16 + ln;
        if constexpr (COUT_F32)
          ((float*)C)[(size_t)m * ldc + n] = acc[i][j][r];
        else
          ((u16*)C)[(size_t)m * ldc + n] = f2bf(acc[i][j][r]);
      }
}

// ---------------------------------------------------------------------------
// Causal flash attention (MFMA), fixed-base softmax, transposed score path
// (S^T = K·Q^T, P^T built in-register as B-frag, O^T = V^T·P^T — no LDS relay).
// Q-tile 128 (2 strips/wave), K-tile 64, register-prefetch double buffer.
// Grid 512: blocks bx and bx+256 are complementary (qt sums to 31) and same
// head -> co-resident pairs have constant total work (66 iters) + shared L2.
// ---------------------------------------------------------------------------
struct StageRegs { uint4 k0, k1, v0, v1; };

__device__ __forceinline__ StageRegs attn_stage_load(
    const u16* __restrict__ qk, const u16* __restrict__ vT,
    int h, int kbase, int tid) {
  StageRegs s;
  {
    int key = tid >> 2, seg = (tid & 3) * 16;
    const u16* kp = qk + (size_t)(kbase + key) * 2048 + 1024 + h * 64 + seg;
    s.k0 = *(const uint4*)kp;
    s.k1 = *(const uint4*)(kp + 8);
  }
  {
    int kh = tid >> 7, d = (tid >> 1) & 63, sg = (tid & 1) * 16;
    const u16* vp = vT + (size_t)(h * 64 + d) * 4096 + kbase + kh * 32 + sg;
    s.v0 = *(const uint4*)vp;
    s.v1 = *(const uint4*)(vp + 8);
  }
  return s;
}

__global__ __launch_bounds__(256, 2) void attn_fwd(
    const u16* __restrict__ qk, const u16* __restrict__ vT, u16* __restrict__ y)
{
  __shared__ u16 Ks[2][2][64][40];     // [buf][d-half][key][d%32] pad 40
  __shared__ u16 Vt[2][2][64][40];     // [buf][pi-key-half][d][pos%32]

  const int tid  = threadIdx.x;
  const int wave = tid >> 6, lane = tid & 63;
  const int quad = lane >> 4, ln = lane & 15;
  const int bx = blockIdx.x;
  // complementary pairing: bx<256 -> qt 31..16 (heavy), bx>=256 -> qt 0..15
  const int qt = (bx < 256) ? (31 - (bx >> 4)) : ((bx - 256) >> 4);
  const int h  = bx & 15;
  const float C1 = 0.18033688f;        // 0.125 * log2(e)

  const int sq0[2] = { qt * 128 + wave * 32, qt * 128 + wave * 32 + 16 };

  bf16x8 qa[2][2];
#pragma unroll
  for (int s = 0; s < 2; ++s) {
    const u16* qrow = qk + (size_t)(sq0[s] + ln) * 2048 + h * 64;
    qa[s][0] = *(const bf16x8*)(qrow + quad * 8);
    qa[s][1] = *(const bf16x8*)(qrow + 32 + quad * 8);
  }

  f32x4 o[2][4] = {};                  // O^T tiles: [strip][d-tile]; row=d, col=qrow
  float l_i[2] = {0.f, 0.f};           // per-lane partial l for qrow=ln

  StageRegs st = attn_stage_load(qk, vT, h, 0, tid);
  const int ktmax = 2 * qt + 1;
  int b = 0;
  for (int kt = 0; kt <= ktmax; ++kt, b ^= 1) {
    {
      int key = tid >> 2, seg = (tid & 3) * 16;
      int kh = seg >> 5, off = seg & 31;
      *(uint4*)&Ks[b][kh][key][off]     = st.k0;
      *(uint4*)&Ks[b][kh][key][off + 8] = st.k1;
      int vh = tid >> 7, d = (tid >> 1) & 63, sg = (tid & 1) * 16;
      *(uint4*)&Vt[b][vh][d][sg]     = st.v0;
      *(uint4*)&Vt[b][vh][d][sg + 8] = st.v1;
    }
    __syncthreads();
    if (kt < ktmax) st = attn_stage_load(qk, vT, h, (kt + 1) * 64, tid);

    bf16x8 kf[2][4], vb[2][4];
#pragma unroll
    for (int hf = 0; hf < 2; ++hf)
#pragma unroll
      for (int c = 0; c < 4; ++c) {
        kf[hf][c] = *(const bf16x8*)&Ks[b][hf][c * 16 + ln][quad * 8];
        vb[hf][c] = *(const bf16x8*)&Vt[b][hf][c * 16 + ln][quad * 8];
      }

    bool act[2];
#pragma unroll
    for (int s = 0; s < 2; ++s) act[s] = (kt * 64 <= sq0[s] + 15);

    bf16x8 pb[2][2];
#pragma unroll
    for (int s = 0; s < 2; ++s) {
      if (!act[s]) continue;           // wave-uniform
      f32x4 sv[4];
#pragma unroll
      for (int t = 0; t < 4; ++t) {
        f32x4 z = {0.f, 0.f, 0.f, 0.f};
        z = __builtin_amdgcn_mfma_f32_16x16x32_bf16(kf[0][t], qa[s][0], z, 0, 0, 0);
        z = __builtin_amdgcn_mfma_f32_16x16x32_bf16(kf[1][t], qa[s][1], z, 0, 0, 0);
        sv[t] = z;                     // row=key=t*16+quad*4+r, col=qrow=ln
      }
      float p[4][4];                   // [t][r]
      if (kt * 64 + 63 > sq0[s]) {
        const int qr = sq0[s] + ln;
#pragma unroll
        for (int t = 0; t < 4; ++t) {
          int keyb = kt * 64 + t * 16 + quad * 4;
#pragma unroll
          for (int r = 0; r < 4; ++r) {
            float arg = (keyb + r > qr) ? -200.0f : fmaf(sv[t][r], C1, -46.0f);
            p[t][r] = fexp2(arg);
          }
        }
      } else {
#pragma unroll
        for (int t = 0; t < 4; ++t)
#pragma unroll
          for (int r = 0; r < 4; ++r)
            p[t][r] = fexp2(fmaf(sv[t][r], C1, -46.0f));
      }
#pragma unroll
      for (int t = 0; t < 4; ++t)
        l_i[s] += (p[t][0] + p[t][1]) + (p[t][2] + p[t][3]);
#pragma unroll
      for (int H = 0; H < 2; ++H) {
        union { unsigned u[4]; bf16x8 v; } pk;
        pk.u[0] = pkbf(p[2 * H][0],     p[2 * H][1]);
        pk.u[1] = pkbf(p[2 * H][2],     p[2 * H][3]);
        pk.u[2] = pkbf(p[2 * H + 1][0], p[2 * H + 1][1]);
        pk.u[3] = pkbf(p[2 * H + 1][2], p[2 * H + 1][3]);
        pb[s][H] = pk.v;
      }
    }

#pragma unroll
    for (int s = 0; s < 2; ++s) {
      if (!act[s]) continue;
#pragma unroll
      for (int dt = 0; dt < 4; ++dt) {
        f32x4 z = o[s][dt];
        z = __builtin_amdgcn_mfma_f32_16x16x32_bf16(vb[0][dt], pb[s][0], z, 0, 0, 0);
        z = __builtin_amdgcn_mfma_f32_16x16x32_bf16(vb[1][dt], pb[s][1], z, 0, 0, 0);
        o[s][dt] = z;
      }
    }
  }

#pragma unroll
  for (int s = 0; s < 2; ++s) {
    l_i[s] += __shfl_xor(l_i[s], 16);
    l_i[s] += __shfl_xor(l_i[s], 32);
    float inv = 1.0f / l_i[s];
    int rowg = sq0[s] + ln;
#pragma unroll
    for (int dt = 0; dt < 4; ++dt)
#pragma unroll
      for (int r = 0; r < 4; ++r)
        y[(size_t)rowg * 1024 + h * 64 + dt * 16 + quad * 4 + r] = f2bf(o[s][dt][r] * inv);
  }
}

extern "C" void kernel_launch(void* const* d_in, const int* in_sizes, int n_in,
                              void* d_out, int out_size, void* d_ws, size_t ws_size,
                              hipStream_t stream) {
  const float* x      = (const float*)d_in[0];   // [4096,1024] fp32
  const float* w_attn = (const float*)d_in[1];   // [3072,1024] fp32
  const float* w_proj = (const float*)d_in[2];   // [1024,1024] fp32

  char* ws = (char*)d_ws;
  u16* qk = (u16*)ws;                        // 16 MiB [4096][2048]
  u16* vT = (u16*)(ws + (16u << 20));        //  8 MiB [1024][4096] pi-permuted

  if (ws_size >= (size_t)(40u << 20)) {
    u16* wpb = (u16*)(ws + (24u << 20));     //  2 MiB bf16 w_proj
    u16* xb  = (u16*)(ws + (26u << 20));     //  8 MiB bf16 x   (dead after GEMM1)
    u16* wab = (u16*)(ws + (34u << 20));     //  6 MiB bf16 w_attn (dead after GEMM1)
    u16* y   = (u16*)(ws + (26u << 20));     //  8 MiB, overlays xb (lifetime-disjoint)

    cvt3<<<4096, 256, 0, stream>>>(x, w_attn, w_proj, xb, wab, wpb);
    gemm_lds<false, true><<<dim3(24, 32), 256, 0, stream>>>(
        xb, wab, qk, vT, 4096, 3072, 1024, 2048);
    attn_fwd<<<dim3(512), 256, 0, stream>>>(qk, vT, y);
    gemm_t64<true><<<dim3(16, 64), 256, 0, stream>>>(
        y, wpb, d_out, 4096, 1024, 1024, 1024);
  } else {
    u16* y = (u16*)(ws + (24u << 20));
    gemm_bt<true, true, false, true><<<dim3(24, 32), 256, 0, stream>>>(
        x, w_attn, qk, vT, 4096, 3072, 1024, 2048);
    attn_fwd<<<dim3(512), 256, 0, stream>>>(qk, vT, y);
    gemm_bt<false, true, true, false><<<dim3(8, 32), 256, 0, stream>>>(
        y, w_proj, d_out, nullptr, 4096, 1024, 1024, 1024);
  }
}